// Round 1
// baseline (247.491 us; speedup 1.0000x reference)
//
#include <hip/hip_runtime.h>
#include <hip/hip_bf16.h>
#include <stdint.h>

#define BB 2
#define SS 2048
#define HH 1024
#define NHH 16
#define HDD 64
#define MM (BB*SS)      // 4096
#define N1 (3*HH)       // 3072

using bf16 = __hip_bfloat16;
typedef __attribute__((ext_vector_type(8))) short bf16x8;
typedef __attribute__((ext_vector_type(4))) float f32x4;

__device__ inline unsigned short f2bfu(float f) {
  union { bf16 h; unsigned short u; } c;
  c.h = __float2bfloat16(f);
  return c.u;
}

__device__ inline void load_lds16(const void* g, void* l) {
  __builtin_amdgcn_global_load_lds(
      (const __attribute__((address_space(1))) void*)g,
      (__attribute__((address_space(3))) void*)l, 16, 0, 0);
}

__device__ inline f32x4 mfma16(bf16x8 a, bf16x8 b, f32x4 c) {
  return __builtin_amdgcn_mfma_f32_16x16x32_bf16(a, b, c, 0, 0, 0);
}

// ---------------- fp32 -> bf16 convert ----------------
__global__ __launch_bounds__(256) void cvt_f32_bf16(const float* __restrict__ in,
                                                    unsigned short* __restrict__ out,
                                                    int n4) {
  int i = blockIdx.x * blockDim.x + threadIdx.x;
  int st = gridDim.x * blockDim.x;
  for (; i < n4; i += st) {
    float4 v = reinterpret_cast<const float4*>(in)[i];
    ushort4 o;
    o.x = f2bfu(v.x); o.y = f2bfu(v.y); o.z = f2bfu(v.z); o.w = f2bfu(v.w);
    reinterpret_cast<ushort4*>(out)[i] = o;
  }
}

// ---------------- GEMM: C[m][n] = sum_k A[m][k]*Bt[n][k] + bias[n] ----------------
// A: [Mdim][Kdim] bf16 row-major; Bt: [Ndim][Kdim] bf16 row-major.
// 128x128 tile, BK=32, 256 threads = 4 waves in 2x2, each wave 64x64 (4x4 frags).
template <bool OUT_BF16>
__global__ __launch_bounds__(256) void gemm_bt(const unsigned short* __restrict__ A,
                                               const unsigned short* __restrict__ Bt,
                                               const float* __restrict__ bias,
                                               void* __restrict__ Cv,
                                               int Ndim, int Kdim) {
  __shared__ __align__(16) unsigned short As[128 * 32];
  __shared__ __align__(16) unsigned short Bs[128 * 32];

  const int tid = threadIdx.x;
  const int wave = tid >> 6, lane = tid & 63;
  const int m0 = blockIdx.x * 128;
  const int n0 = blockIdx.y * 128;
  const int wm = (wave >> 1) * 64, wn = (wave & 1) * 64;
  const int lrow = lane & 15;
  const int lk8 = (lane >> 4) * 8;
  const int r4 = (lane >> 4) * 4;

  f32x4 acc[4][4];
  const f32x4 z = {0.f, 0.f, 0.f, 0.f};
  for (int i = 0; i < 4; ++i)
    for (int j = 0; j < 4; ++j) acc[i][j] = z;

  for (int k0 = 0; k0 < Kdim; k0 += 32) {
#pragma unroll
    for (int it = 0; it < 2; ++it) {
      int idx = it * 256 + tid;
      int row = idx >> 2, seg = idx & 3;
      load_lds16(A + (size_t)(m0 + row) * Kdim + k0 + seg * 8, &As[row * 32 + seg * 8]);
      load_lds16(Bt + (size_t)(n0 + row) * Kdim + k0 + seg * 8, &Bs[row * 32 + seg * 8]);
    }
    __syncthreads();

    bf16x8 af[4], bfr[4];
#pragma unroll
    for (int i = 0; i < 4; ++i)
      af[i] = *reinterpret_cast<const bf16x8*>(&As[(wm + i * 16 + lrow) * 32 + lk8]);
#pragma unroll
    for (int j = 0; j < 4; ++j)
      bfr[j] = *reinterpret_cast<const bf16x8*>(&Bs[(wn + j * 16 + lrow) * 32 + lk8]);
#pragma unroll
    for (int i = 0; i < 4; ++i)
#pragma unroll
      for (int j = 0; j < 4; ++j)
        acc[i][j] = mfma16(af[i], bfr[j], acc[i][j]);
    __syncthreads();
  }

  // epilogue: C/D layout col=lane&15, row=(lane>>4)*4+r
#pragma unroll
  for (int i = 0; i < 4; ++i) {
#pragma unroll
    for (int j = 0; j < 4; ++j) {
      int col = n0 + wn + j * 16 + lrow;
      float bv = bias[col];
#pragma unroll
      for (int r = 0; r < 4; ++r) {
        int row = m0 + wm + i * 16 + r4 + r;
        float v = acc[i][j][r] + bv;
        if (OUT_BF16) {
          ((unsigned short*)Cv)[(size_t)row * Ndim + col] = f2bfu(v);
        } else {
          ((float*)Cv)[(size_t)row * Ndim + col] = v;
        }
      }
    }
  }
}

// ---------------- Flash attention ----------------
// mixed: [B*S][3072] bf16, per head h: q at col h*192, k at +64, v at +128.
// grid: (S/64, B*NH); block 256 = 4 waves; wave w handles q-rows w*16..w*16+15.
__global__ __launch_bounds__(256) void attn_kernel(const unsigned short* __restrict__ mixed,
                                                   const float* __restrict__ mask,
                                                   unsigned short* __restrict__ ctx) {
  __shared__ __align__(16) unsigned short Qs[64 * 64];
  __shared__ __align__(16) unsigned short Ks[64 * 64];
  __shared__ __align__(16) unsigned short Vt[64 * 64];   // [d][k]
  __shared__ __align__(16) unsigned short Ps[4][16 * 64];

  const int tid = threadIdx.x, wave = tid >> 6, lane = tid & 63;
  const int q0 = blockIdx.x * 64;
  const int bh = blockIdx.y;
  const int b = bh / NHH, h = bh % NHH;

  const unsigned short* qbase = mixed + (size_t)(b * SS) * N1 + h * 192;
  const unsigned short* kbase = qbase + 64;
  const unsigned short* vbase = qbase + 128;
  const float* mbase = mask + (size_t)b * SS * SS;

  const int lrow = lane & 15;
  const int lk8 = (lane >> 4) * 8;
  const int r4 = (lane >> 4) * 4;

  // stage Q tile [64][64]
#pragma unroll
  for (int it = 0; it < 2; ++it) {
    int idx = it * 256 + tid;
    int row = idx >> 3, seg = idx & 7;
    load_lds16(qbase + (size_t)(q0 + row) * N1 + seg * 8, &Qs[row * 64 + seg * 8]);
  }

  f32x4 oacc[4];
  const f32x4 z = {0.f, 0.f, 0.f, 0.f};
  for (int fd = 0; fd < 4; ++fd) oacc[fd] = z;
  float mrun[4], lrun[4];
  for (int r = 0; r < 4; ++r) { mrun[r] = -1e30f; lrun[r] = 0.f; }

  for (int kt = 0; kt < SS / 64; ++kt) {
    const int krow0 = kt * 64;
    // stage K tile [64][64]
#pragma unroll
    for (int it = 0; it < 2; ++it) {
      int idx = it * 256 + tid;
      int row = idx >> 3, seg = idx & 7;
      load_lds16(kbase + (size_t)(krow0 + row) * N1 + seg * 8, &Ks[row * 64 + seg * 8]);
    }
    // stage V transposed: Vt[d][k]
    {
      int krow = tid & 63, dg = wave;  // dg covers cols dg*16..+15
      const unsigned short* vp = vbase + (size_t)(krow0 + krow) * N1 + dg * 16;
      union { bf16x8 v; unsigned short u[8]; } U0, U1;
      U0.v = *reinterpret_cast<const bf16x8*>(vp);
      U1.v = *reinterpret_cast<const bf16x8*>(vp + 8);
#pragma unroll
      for (int j = 0; j < 8; ++j) Vt[(dg * 16 + j) * 64 + krow] = U0.u[j];
#pragma unroll
      for (int j = 0; j < 8; ++j) Vt[(dg * 16 + 8 + j) * 64 + krow] = U1.u[j];
    }
    __syncthreads();

    // QK^T: S-tile rows wave*16..+15 x 64 cols
    f32x4 sacc[4];
    for (int n = 0; n < 4; ++n) sacc[n] = z;
    bf16x8 aq0 = *reinterpret_cast<const bf16x8*>(&Qs[(wave * 16 + lrow) * 64 + lk8]);
    bf16x8 aq1 = *reinterpret_cast<const bf16x8*>(&Qs[(wave * 16 + lrow) * 64 + 32 + lk8]);
#pragma unroll
    for (int n = 0; n < 4; ++n) {
      bf16x8 bk0 = *reinterpret_cast<const bf16x8*>(&Ks[(n * 16 + lrow) * 64 + lk8]);
      bf16x8 bk1 = *reinterpret_cast<const bf16x8*>(&Ks[(n * 16 + lrow) * 64 + 32 + lk8]);
      sacc[n] = mfma16(aq0, bk0, sacc[n]);
      sacc[n] = mfma16(aq1, bk1, sacc[n]);
    }

    // scale + mask + online softmax
    float p[4][4];
    float tmax[4] = {-1e30f, -1e30f, -1e30f, -1e30f};
#pragma unroll
    for (int n = 0; n < 4; ++n) {
#pragma unroll
      for (int r = 0; r < 4; ++r) {
        int qq = q0 + wave * 16 + r4 + r;
        int kk = krow0 + n * 16 + lrow;
        float mval = mbase[(size_t)qq * SS + kk];
        float sv = sacc[n][r] * 0.125f;
        sv = sv * mval - 10000.f * (1.f - mval);
        p[n][r] = sv;
        tmax[r] = fmaxf(tmax[r], sv);
      }
    }
#pragma unroll
    for (int r = 0; r < 4; ++r) {
      float t = tmax[r];
      t = fmaxf(t, __shfl_xor(t, 1, 64));
      t = fmaxf(t, __shfl_xor(t, 2, 64));
      t = fmaxf(t, __shfl_xor(t, 4, 64));
      t = fmaxf(t, __shfl_xor(t, 8, 64));
      tmax[r] = t;
    }
    float alpha[4];
#pragma unroll
    for (int r = 0; r < 4; ++r) {
      float mnew = fmaxf(mrun[r], tmax[r]);
      alpha[r] = __expf(mrun[r] - mnew);
      mrun[r] = mnew;
    }
    float rsum[4] = {0.f, 0.f, 0.f, 0.f};
#pragma unroll
    for (int n = 0; n < 4; ++n) {
#pragma unroll
      for (int r = 0; r < 4; ++r) {
        float pv = __expf(p[n][r] - mrun[r]);
        p[n][r] = pv;
        rsum[r] += pv;
      }
    }
#pragma unroll
    for (int r = 0; r < 4; ++r) {
      float t = rsum[r];
      t += __shfl_xor(t, 1, 64);
      t += __shfl_xor(t, 2, 64);
      t += __shfl_xor(t, 4, 64);
      t += __shfl_xor(t, 8, 64);
      lrun[r] = lrun[r] * alpha[r] + t;
    }
    // rescale O
#pragma unroll
    for (int fd = 0; fd < 4; ++fd)
#pragma unroll
      for (int r = 0; r < 4; ++r) oacc[fd][r] *= alpha[r];
    // write P (bf16) to wave-private LDS region
#pragma unroll
    for (int n = 0; n < 4; ++n)
#pragma unroll
      for (int r = 0; r < 4; ++r)
        Ps[wave][(r4 + r) * 64 + n * 16 + lrow] = f2bfu(p[n][r]);
    __syncthreads();

    // PV: O += P[16x64] * V[64x64]
    bf16x8 ap0 = *reinterpret_cast<const bf16x8*>(&Ps[wave][lrow * 64 + lk8]);
    bf16x8 ap1 = *reinterpret_cast<const bf16x8*>(&Ps[wave][lrow * 64 + 32 + lk8]);
#pragma unroll
    for (int fd = 0; fd < 4; ++fd) {
      bf16x8 bv0 = *reinterpret_cast<const bf16x8*>(&Vt[(fd * 16 + lrow) * 64 + lk8]);
      bf16x8 bv1 = *reinterpret_cast<const bf16x8*>(&Vt[(fd * 16 + lrow) * 64 + 32 + lk8]);
      oacc[fd] = mfma16(ap0, bv0, oacc[fd]);
      oacc[fd] = mfma16(ap1, bv1, oacc[fd]);
    }
    __syncthreads();
  }

  // epilogue: ctx[b][s][h*64+d] bf16
#pragma unroll
  for (int r = 0; r < 4; ++r) {
    float inv = 1.f / lrun[r];
    int qq = q0 + wave * 16 + r4 + r;
    unsigned short* cp = ctx + (size_t)(b * SS + qq) * HH + h * HDD;
#pragma unroll
    for (int fd = 0; fd < 4; ++fd)
      cp[fd * 16 + lrow] = f2bfu(oacc[fd][r] * inv);
  }
}

extern "C" void kernel_launch(void* const* d_in, const int* in_sizes, int n_in,
                              void* d_out, int out_size, void* d_ws, size_t ws_size,
                              hipStream_t stream) {
  const float* hs      = (const float*)d_in[0];
  const float* mask    = (const float*)d_in[1];
  const float* qkv_w   = (const float*)d_in[2];
  const float* qkv_b   = (const float*)d_in[3];
  const float* dense_w = (const float*)d_in[4];
  const float* dense_b = (const float*)d_in[5];
  float* out = (float*)d_out;

  char* ws = (char*)d_ws;
  unsigned short* hs_b     = (unsigned short*)(ws);                 // 4096x1024
  unsigned short* qkvw_b   = (unsigned short*)(ws + 8388608);       // 3072x1024
  unsigned short* densew_b = (unsigned short*)(ws + 14680064);      // 1024x1024
  unsigned short* mixed_b  = (unsigned short*)(ws + 16777216);      // 4096x3072
  unsigned short* ctx_b    = (unsigned short*)(ws + 41943040);      // 4096x1024

  // converts
  cvt_f32_bf16<<<2048, 256, 0, stream>>>(hs, hs_b, (MM * HH) / 4);
  cvt_f32_bf16<<<2048, 256, 0, stream>>>(qkv_w, qkvw_b, (N1 * HH) / 4);
  cvt_f32_bf16<<<1024, 256, 0, stream>>>(dense_w, densew_b, (HH * HH) / 4);

  // GEMM1: mixed = hs @ qkv_w^T + qkv_b   (bf16 out)
  gemm_bt<true><<<dim3(MM / 128, N1 / 128), 256, 0, stream>>>(
      hs_b, qkvw_b, qkv_b, mixed_b, N1, HH);

  // attention
  attn_kernel<<<dim3(SS / 64, BB * NHH), 256, 0, stream>>>(mixed_b, mask, ctx_b);

  // GEMM2: out = ctx @ dense_w^T + dense_b  (fp32 out)
  gemm_bt<false><<<dim3(MM / 128, HH / 128), 256, 0, stream>>>(
      ctx_b, densew_b, dense_b, out, HH, HH);
}

// Round 2
// 212.916 us; speedup vs baseline: 1.1624x; 1.1624x over previous
//
#include <hip/hip_runtime.h>
#include <hip/hip_bf16.h>
#include <stdint.h>

#define BB 2
#define SS 2048
#define HH 1024
#define NHH 16
#define HDD 64
#define MM (BB*SS)      // 4096
#define N1 (3*HH)       // 3072
#define NT (SS/64)      // 32 kv tiles

using bf16 = __hip_bfloat16;
typedef __attribute__((ext_vector_type(8))) short bf16x8;
typedef __attribute__((ext_vector_type(4))) float f32x4;

__device__ inline unsigned short f2bfu(float f) {
  union { bf16 h; unsigned short u; } c;
  c.h = __float2bfloat16(f);
  return c.u;
}

__device__ inline void load_lds16(const void* g, void* l) {
  __builtin_amdgcn_global_load_lds(
      (const __attribute__((address_space(1))) void*)g,
      (__attribute__((address_space(3))) void*)l, 16, 0, 0);
}

__device__ inline f32x4 mfma16(bf16x8 a, bf16x8 b, f32x4 c) {
  return __builtin_amdgcn_mfma_f32_16x16x32_bf16(a, b, c, 0, 0, 0);
}

// ---------------- fp32 -> bf16 convert ----------------
__global__ __launch_bounds__(256) void cvt_f32_bf16(const float* __restrict__ in,
                                                    unsigned short* __restrict__ out,
                                                    int n4) {
  int i = blockIdx.x * blockDim.x + threadIdx.x;
  int st = gridDim.x * blockDim.x;
  for (; i < n4; i += st) {
    float4 v = reinterpret_cast<const float4*>(in)[i];
    ushort4 o;
    o.x = f2bfu(v.x); o.y = f2bfu(v.y); o.z = f2bfu(v.z); o.w = f2bfu(v.w);
    reinterpret_cast<ushort4*>(out)[i] = o;
  }
}

// ---------------- mask tile flags: 1 if 64x64 tile is all ones ----------------
// grid = B*32*32 blocks of 256; tile (b, qt, kt)
__global__ __launch_bounds__(256) void mask_flags_kernel(const float* __restrict__ mask,
                                                         unsigned char* __restrict__ flags) {
  int t = blockIdx.x;
  int b = t >> 10, qt = (t >> 5) & 31, kt = t & 31;
  const float* mb = mask + ((size_t)b * SS + qt * 64) * SS + kt * 64;
  int row = threadIdx.x >> 2, c0 = (threadIdx.x & 3) * 16;
  int ok = 1;
#pragma unroll
  for (int j = 0; j < 4; ++j) {
    float4 v = *reinterpret_cast<const float4*>(mb + (size_t)row * SS + c0 + j * 4);
    ok &= (v.x == 1.f) & (v.y == 1.f) & (v.z == 1.f) & (v.w == 1.f);
  }
  ok = __all(ok);
  __shared__ int s[4];
  if ((threadIdx.x & 63) == 0) s[threadIdx.x >> 6] = ok;
  __syncthreads();
  if (threadIdx.x == 0) flags[t] = (unsigned char)(s[0] & s[1] & s[2] & s[3]);
}

// ---------------- GEMM: C[m][n] = sum_k A[m][k]*Bt[n][k] + bias[n] ----------------
template <bool OUT_BF16>
__global__ __launch_bounds__(256) void gemm_bt(const unsigned short* __restrict__ A,
                                               const unsigned short* __restrict__ Bt,
                                               const float* __restrict__ bias,
                                               void* __restrict__ Cv,
                                               int Ndim, int Kdim) {
  __shared__ __align__(16) unsigned short As[128 * 32];
  __shared__ __align__(16) unsigned short Bs[128 * 32];

  const int tid = threadIdx.x;
  const int wave = tid >> 6, lane = tid & 63;
  const int m0 = blockIdx.x * 128;
  const int n0 = blockIdx.y * 128;
  const int wm = (wave >> 1) * 64, wn = (wave & 1) * 64;
  const int lrow = lane & 15;
  const int lk8 = (lane >> 4) * 8;
  const int r4 = (lane >> 4) * 4;

  f32x4 acc[4][4];
  const f32x4 z = {0.f, 0.f, 0.f, 0.f};
  for (int i = 0; i < 4; ++i)
    for (int j = 0; j < 4; ++j) acc[i][j] = z;

  for (int k0 = 0; k0 < Kdim; k0 += 32) {
#pragma unroll
    for (int it = 0; it < 2; ++it) {
      int idx = it * 256 + tid;
      int row = idx >> 2, seg = idx & 3;
      load_lds16(A + (size_t)(m0 + row) * Kdim + k0 + seg * 8, &As[row * 32 + seg * 8]);
      load_lds16(Bt + (size_t)(n0 + row) * Kdim + k0 + seg * 8, &Bs[row * 32 + seg * 8]);
    }
    __syncthreads();

    bf16x8 af[4], bfr[4];
#pragma unroll
    for (int i = 0; i < 4; ++i)
      af[i] = *reinterpret_cast<const bf16x8*>(&As[(wm + i * 16 + lrow) * 32 + lk8]);
#pragma unroll
    for (int j = 0; j < 4; ++j)
      bfr[j] = *reinterpret_cast<const bf16x8*>(&Bs[(wn + j * 16 + lrow) * 32 + lk8]);
#pragma unroll
    for (int i = 0; i < 4; ++i)
#pragma unroll
      for (int j = 0; j < 4; ++j)
        acc[i][j] = mfma16(af[i], bfr[j], acc[i][j]);
    __syncthreads();
  }

#pragma unroll
  for (int i = 0; i < 4; ++i) {
#pragma unroll
    for (int j = 0; j < 4; ++j) {
      int col = n0 + wn + j * 16 + lrow;
      float bv = bias[col];
#pragma unroll
      for (int r = 0; r < 4; ++r) {
        int row = m0 + wm + i * 16 + r4 + r;
        float v = acc[i][j][r] + bv;
        if (OUT_BF16) {
          ((unsigned short*)Cv)[(size_t)row * Ndim + col] = f2bfu(v);
        } else {
          ((float*)Cv)[(size_t)row * Ndim + col] = v;
        }
      }
    }
  }
}

// ---------------- Flash attention (swizzled LDS, 2-phase pipeline) ----------------
// Swizzle: element (row, col) of a [R][64] bf16 tile lives at LDS element
//   row*64 + ((c8 ^ (row&7))<<3) + (col&7),  c8 = col>>3.
// global_load_lds keeps the LDS side linear; the global source column segment is
// pre-XORed instead (same involution) per rule #21.
__global__ __launch_bounds__(256) void attn_kernel(const unsigned short* __restrict__ mixed,
                                                   const float* __restrict__ mask,
                                                   const unsigned char* __restrict__ flags,
                                                   unsigned short* __restrict__ ctx) {
  __shared__ __align__(16) unsigned short Qs[64 * 64];
  __shared__ __align__(16) unsigned short Ks[2][64 * 64];
  __shared__ __align__(16) unsigned short Vt[2][64 * 64];   // [d][k]
  __shared__ __align__(16) unsigned short Ps[4][16 * 64];

  const int tid = threadIdx.x, wave = tid >> 6, lane = tid & 63;
  const int q0 = blockIdx.x * 64;
  const int bh = blockIdx.y;
  const int b = bh / NHH, h = bh % NHH;

  const unsigned short* qbase = mixed + (size_t)(b * SS) * N1 + h * 192;
  const unsigned short* kbase = qbase + 64;
  const unsigned short* vbase = qbase + 128;
  const float* mbase = mask + (size_t)b * SS * SS;
  const unsigned char* fl = flags + ((size_t)b * 32 + blockIdx.x) * 32;

  const int lrow = lane & 15;
  const int lc8 = lane >> 4;          // 0..3 column-segment
  const int r4 = (lane >> 4) * 4;
  const int vrow = lane;              // V stage: k-row this lane loads
  const int dg = wave;                // V stage: d-group (16 cols) this wave covers

  // ---- prologue: stage Q, K0, V0 ----
#pragma unroll
  for (int it = 0; it < 2; ++it) {
    int idx = it * 256 + tid;
    int row = idx >> 3, seg = idx & 7;
    load_lds16(qbase + (size_t)(q0 + row) * N1 + ((seg ^ (row & 7)) << 3),
               &Qs[row * 64 + seg * 8]);
    load_lds16(kbase + (size_t)(row) * N1 + ((seg ^ (row & 7)) << 3),
               &Ks[0][row * 64 + seg * 8]);
  }
  {
    union { bf16x8 v; unsigned short u[8]; } V0, V1;
    const unsigned short* vp = vbase + (size_t)vrow * N1 + dg * 16;
    V0.v = *reinterpret_cast<const bf16x8*>(vp);
    V1.v = *reinterpret_cast<const bf16x8*>(vp + 8);
#pragma unroll
    for (int j = 0; j < 8; ++j) {
      int d = dg * 16 + j;
      Vt[0][d * 64 + ((((vrow >> 3) ^ (d & 7)) << 3) | (vrow & 7))] = V0.u[j];
    }
#pragma unroll
    for (int j = 0; j < 8; ++j) {
      int d = dg * 16 + 8 + j;
      Vt[0][d * 64 + ((((vrow >> 3) ^ (d & 7)) << 3) | (vrow & 7))] = V1.u[j];
    }
  }
  __syncthreads();

  // Q fragments are loop-invariant: hoist to registers
  const int qr = wave * 16 + lrow;
  const bf16x8 aq0 = *reinterpret_cast<const bf16x8*>(
      &Qs[qr * 64 + ((lc8 ^ (qr & 7)) << 3)]);
  const bf16x8 aq1 = *reinterpret_cast<const bf16x8*>(
      &Qs[qr * 64 + (((lc8 + 4) ^ (qr & 7)) << 3)]);

  f32x4 oacc[4];
  const f32x4 z = {0.f, 0.f, 0.f, 0.f};
  for (int fd = 0; fd < 4; ++fd) oacc[fd] = z;
  float mrun[4], lrun[4];
  for (int r = 0; r < 4; ++r) { mrun[r] = -1e30f; lrun[r] = 0.f; }

  for (int kt = 0; kt < NT; ++kt) {
    const int cur = kt & 1, nxt = cur ^ 1;
    const int krow0 = kt * 64;
    const bool havenext = (kt + 1 < NT);

    // ---- issue next tile's loads (overlap with compute) ----
    union { bf16x8 v; unsigned short u[8]; } Vn0, Vn1;
    if (havenext) {
#pragma unroll
      for (int it = 0; it < 2; ++it) {
        int idx = it * 256 + tid;
        int row = idx >> 3, seg = idx & 7;
        load_lds16(kbase + (size_t)(krow0 + 64 + row) * N1 + ((seg ^ (row & 7)) << 3),
                   &Ks[nxt][row * 64 + seg * 8]);
      }
      const unsigned short* vp = vbase + (size_t)(krow0 + 64 + vrow) * N1 + dg * 16;
      Vn0.v = *reinterpret_cast<const bf16x8*>(vp);
      Vn1.v = *reinterpret_cast<const bf16x8*>(vp + 8);
    }

    // ---- QK^T from Ks[cur] ----
    f32x4 sacc[4];
    for (int n = 0; n < 4; ++n) sacc[n] = z;
#pragma unroll
    for (int n = 0; n < 4; ++n) {
      int kr = n * 16 + lrow;
      bf16x8 bk0 = *reinterpret_cast<const bf16x8*>(
          &Ks[cur][kr * 64 + ((lc8 ^ (kr & 7)) << 3)]);
      bf16x8 bk1 = *reinterpret_cast<const bf16x8*>(
          &Ks[cur][kr * 64 + (((lc8 + 4) ^ (kr & 7)) << 3)]);
      sacc[n] = mfma16(aq0, bk0, sacc[n]);
      sacc[n] = mfma16(aq1, bk1, sacc[n]);
    }

    // ---- scale + mask + online softmax ----
    const bool allones = fl[kt] != 0;
    float p[4][4];
    float tmax[4] = {-1e30f, -1e30f, -1e30f, -1e30f};
    if (allones) {
#pragma unroll
      for (int n = 0; n < 4; ++n)
#pragma unroll
        for (int r = 0; r < 4; ++r) {
          float sv = sacc[n][r] * 0.125f;
          p[n][r] = sv;
          tmax[r] = fmaxf(tmax[r], sv);
        }
    } else {
#pragma unroll
      for (int n = 0; n < 4; ++n)
#pragma unroll
        for (int r = 0; r < 4; ++r) {
          int qq = q0 + wave * 16 + r4 + r;
          int kk = krow0 + n * 16 + lrow;
          float mval = mbase[(size_t)qq * SS + kk];
          float sv = sacc[n][r] * 0.125f;
          sv = sv * mval - 10000.f * (1.f - mval);
          p[n][r] = sv;
          tmax[r] = fmaxf(tmax[r], sv);
        }
    }
#pragma unroll
    for (int r = 0; r < 4; ++r) {
      float t = tmax[r];
      t = fmaxf(t, __shfl_xor(t, 1, 64));
      t = fmaxf(t, __shfl_xor(t, 2, 64));
      t = fmaxf(t, __shfl_xor(t, 4, 64));
      t = fmaxf(t, __shfl_xor(t, 8, 64));
      tmax[r] = t;
    }
    float alpha[4];
#pragma unroll
    for (int r = 0; r < 4; ++r) {
      float mnew = fmaxf(mrun[r], tmax[r]);
      alpha[r] = __expf(mrun[r] - mnew);
      mrun[r] = mnew;
    }
    float rsum[4] = {0.f, 0.f, 0.f, 0.f};
#pragma unroll
    for (int n = 0; n < 4; ++n)
#pragma unroll
      for (int r = 0; r < 4; ++r) {
        float pv = __expf(p[n][r] - mrun[r]);
        p[n][r] = pv;
        rsum[r] += pv;
      }
#pragma unroll
    for (int r = 0; r < 4; ++r) {
      float t = rsum[r];
      t += __shfl_xor(t, 1, 64);
      t += __shfl_xor(t, 2, 64);
      t += __shfl_xor(t, 4, 64);
      t += __shfl_xor(t, 8, 64);
      lrun[r] = lrun[r] * alpha[r] + t;
    }
#pragma unroll
    for (int fd = 0; fd < 4; ++fd)
#pragma unroll
      for (int r = 0; r < 4; ++r) oacc[fd][r] *= alpha[r];

    // ---- P -> wave-private LDS (swizzled); no barrier needed (same wave) ----
#pragma unroll
    for (int n = 0; n < 4; ++n)
#pragma unroll
      for (int r = 0; r < 4; ++r) {
        int pr = r4 + r;
        int seg = n * 2 + (lrow >> 3);
        Ps[wave][pr * 64 + (((seg ^ (pr & 7)) << 3) | (lrow & 7))] = f2bfu(p[n][r]);
      }

    // ---- PV from Vt[cur] ----
    bf16x8 ap0 = *reinterpret_cast<const bf16x8*>(
        &Ps[wave][lrow * 64 + ((lc8 ^ (lrow & 7)) << 3)]);
    bf16x8 ap1 = *reinterpret_cast<const bf16x8*>(
        &Ps[wave][lrow * 64 + (((lc8 + 4) ^ (lrow & 7)) << 3)]);
#pragma unroll
    for (int fd = 0; fd < 4; ++fd) {
      int vr = fd * 16 + lrow;
      bf16x8 bv0 = *reinterpret_cast<const bf16x8*>(
          &Vt[cur][vr * 64 + ((lc8 ^ (vr & 7)) << 3)]);
      bf16x8 bv1 = *reinterpret_cast<const bf16x8*>(
          &Vt[cur][vr * 64 + (((lc8 + 4) ^ (vr & 7)) << 3)]);
      oacc[fd] = mfma16(ap0, bv0, oacc[fd]);
      oacc[fd] = mfma16(ap1, bv1, oacc[fd]);
    }

    // ---- write next V tile (reg->LDS), then single barrier ----
    if (havenext) {
#pragma unroll
      for (int j = 0; j < 8; ++j) {
        int d = dg * 16 + j;
        Vt[nxt][d * 64 + ((((vrow >> 3) ^ (d & 7)) << 3) | (vrow & 7))] = Vn0.u[j];
      }
#pragma unroll
      for (int j = 0; j < 8; ++j) {
        int d = dg * 16 + 8 + j;
        Vt[nxt][d * 64 + ((((vrow >> 3) ^ (d & 7)) << 3) | (vrow & 7))] = Vn1.u[j];
      }
    }
    __syncthreads();
  }

  // ---- epilogue ----
#pragma unroll
  for (int r = 0; r < 4; ++r) {
    float inv = 1.f / lrun[r];
    int qq = q0 + wave * 16 + r4 + r;
    unsigned short* cp = ctx + (size_t)(b * SS + qq) * HH + h * HDD;
#pragma unroll
    for (int fd = 0; fd < 4; ++fd)
      cp[fd * 16 + lrow] = f2bfu(oacc[fd][r] * inv);
  }
}

extern "C" void kernel_launch(void* const* d_in, const int* in_sizes, int n_in,
                              void* d_out, int out_size, void* d_ws, size_t ws_size,
                              hipStream_t stream) {
  const float* hs      = (const float*)d_in[0];
  const float* mask    = (const float*)d_in[1];
  const float* qkv_w   = (const float*)d_in[2];
  const float* qkv_b   = (const float*)d_in[3];
  const float* dense_w = (const float*)d_in[4];
  const float* dense_b = (const float*)d_in[5];
  float* out = (float*)d_out;

  char* ws = (char*)d_ws;
  unsigned short* hs_b     = (unsigned short*)(ws);                 // 4096x1024
  unsigned short* qkvw_b   = (unsigned short*)(ws + 8388608);       // 3072x1024
  unsigned short* densew_b = (unsigned short*)(ws + 14680064);      // 1024x1024
  unsigned short* mixed_b  = (unsigned short*)(ws + 16777216);      // 4096x3072
  unsigned short* ctx_b    = (unsigned short*)(ws + 41943040);      // 4096x1024
  unsigned char*  flags    = (unsigned char*)(ws + 50331648);       // 2048 bytes

  // converts + mask flags
  cvt_f32_bf16<<<2048, 256, 0, stream>>>(hs, hs_b, (MM * HH) / 4);
  cvt_f32_bf16<<<2048, 256, 0, stream>>>(qkv_w, qkvw_b, (N1 * HH) / 4);
  cvt_f32_bf16<<<1024, 256, 0, stream>>>(dense_w, densew_b, (HH * HH) / 4);
  mask_flags_kernel<<<BB * 32 * 32, 256, 0, stream>>>(mask, flags);

  // GEMM1: mixed = hs @ qkv_w^T + qkv_b   (bf16 out)
  gemm_bt<true><<<dim3(MM / 128, N1 / 128), 256, 0, stream>>>(
      hs_b, qkvw_b, qkv_b, mixed_b, N1, HH);

  // attention
  attn_kernel<<<dim3(SS / 64, BB * NHH), 256, 0, stream>>>(mixed_b, mask, flags, ctx_b);

  // GEMM2: out = ctx @ dense_w^T + dense_b  (fp32 out)
  gemm_bt<false><<<dim3(MM / 128, HH / 128), 256, 0, stream>>>(
      ctx_b, densew_b, dense_b, out, HH, HH);
}